// Round 10
// baseline (373.489 us; speedup 1.0000x reference)
//
#include <hip/hip_runtime.h>

// HMM forward scan, one workgroup per unit u. U=256, N=64, S=4, B=64, T=1024.
// Wave w owns batches [16w,16w+16); lane (q=lane>>4,l=lane&15) owns batch
// b=16w+l and the 16 states j = sig(jt, 4q+r).
//
// R18 = R17 chassis + E-on-VALU. Cost law fitted across R8-R17:
//   MFMA ~36cy wave-issue each (17.5 pipe + ~18 un-fillable block),
//   VALU ~2cy/instr, shfl-ss +~150cy exposed lgkm.
// So: E as 4 MFMAs (144cy) -> 64 VALU fma (128cy, and schedulable);
// ss stays 2 ones-row MFMAs (72cy, no lgkm exposure). 10 MFMAs/step
// (8 R unchained + 2 ss) + ~132 VALU instrs ~= 620cy predicted.
// Components individually proven: E-VALU (R12), MFMA-ss + lag-2 E (R17).
//  - E_{t+2} computed on VALU from f32 cBem (MORE accurate than the old
//    bf16 E-MFMA path), ping-ponged EvA/EvB by slot parity (R17).
//  - V-phase reads ordered oldest-first (R17).
//  - Rescale mul only at slot 0, compile-time folded (R17).
// Unnormalized recursion + exact pow2 octet rescale + once-per-32 flush
// unchanged (proven R10/R13/R17).

#define U_ 256
#define N_ 64
#define S_ 4
#define B_ 64
#define T_ 1024
#define ROWP 72
#define LN2F 0.69314718055994530942f

typedef __attribute__((ext_vector_type(8))) __bf16 bf16x8;
typedef __attribute__((ext_vector_type(4))) float floatx4;

__device__ __forceinline__ int sig(int jt, int m) {
    return 32 * (jt >> 1) + 4 * (jt & 1) + 8 * (m >> 2) + (m & 3);
}

__launch_bounds__(256, 1)
__global__ void hmm_fwd_kernel(const float* __restrict__ xg,     // [B][T][S]
                               const float* __restrict__ trans,  // [U][N][N]
                               const float* __restrict__ emis,   // [U][N][S]
                               const float* __restrict__ initk,  // [U][N]
                               float* __restrict__ out)          // [B][T][U]
{
    __shared__ __bf16 AT[N_ * ROWP];
    __shared__ float BemS[N_][S_];
    __shared__ float IS[N_];

    const int bid = blockIdx.x;
    const int u = ((bid & 7) << 5) | (bid >> 3);   // XCD-aware u swizzle
    const int tid = threadIdx.x;
    const int lane = tid & 63;
    const int w = tid >> 6;
    const int q = lane >> 4;
    const int l = lane & 15;

    // ---------------- prologue: softmaxes (one-time) ----------------
    if (tid < 64) {
        const float* rowp = trans + (u * N_ + tid) * N_;
        float v[N_];
        #pragma unroll
        for (int k = 0; k < 16; ++k) {
            floatx4 t4 = *(const floatx4*)(rowp + 4 * k);
            v[4*k] = t4.x; v[4*k+1] = t4.y; v[4*k+2] = t4.z; v[4*k+3] = t4.w;
        }
        float m = v[0];
        #pragma unroll
        for (int j = 1; j < N_; ++j) m = fmaxf(m, v[j]);
        float s = 0.f;
        #pragma unroll
        for (int j = 0; j < N_; ++j) { v[j] = __expf(v[j] - m); s += v[j]; }
        float inv = 1.0f / s;
        #pragma unroll
        for (int j = 0; j < N_; ++j) AT[j * ROWP + tid] = (__bf16)(v[j] * inv);
    } else if (tid < 128) {
        int n = tid - 64;
        floatx4 e4 = *(const floatx4*)(emis + (u * N_ + n) * S_);
        float m = fmaxf(fmaxf(e4.x, e4.y), fmaxf(e4.z, e4.w));
        float a = __expf(e4.x - m), b2 = __expf(e4.y - m);
        float c = __expf(e4.z - m), d = __expf(e4.w - m);
        float inv = 1.0f / (a + b2 + c + d);
        BemS[n][0] = a*inv; BemS[n][1] = b2*inv; BemS[n][2] = c*inv; BemS[n][3] = d*inv;
    } else if (tid < 192) {
        int j = tid - 128;
        float v = initk[u * N_ + j];
        float m = v;
        #pragma unroll
        for (int s = 1; s < 64; s <<= 1) m = fmaxf(m, __shfl_xor(m, s, 64));
        float e = __expf(v - m);
        float ssum = e;
        #pragma unroll
        for (int s = 1; s < 64; s <<= 1) ssum += __shfl_xor(ssum, s, 64);
        IS[j] = e / ssum;
    }
    __syncthreads();

    // ------------- persistent register state -------------
    bf16x8 afrag[4][2];
    #pragma unroll
    for (int jt = 0; jt < 4; ++jt)
        #pragma unroll
        for (int kt = 0; kt < 2; ++kt)
            afrag[jt][kt] = *(const bf16x8*)&AT[sig(jt, l) * ROWP + 32*kt + 8*q];

    // f32 emission coefficients, one floatx4 per owned state (VALU E)
    floatx4 cBem[4][4];
    #pragma unroll
    for (int jt = 0; jt < 4; ++jt)
        #pragma unroll
        for (int r = 0; r < 4; ++r)
            cBem[jt][r] = *(const floatx4*)&BemS[sig(jt, 4*q + r)][0];

    bf16x8 onesf;
    #pragma unroll
    for (int pp = 0; pp < 8; ++pp) onesf[pp] = (__bf16)1.0f;

    // Rv(t) = P0+P1 combined lag-1 on VALU (R13, unchained)
    floatx4 P0[4], P1[4];
    #pragma unroll
    for (int jt = 0; jt < 4; ++jt)
        #pragma unroll
        for (int r = 0; r < 4; ++r) {
            P0[jt][r] = IS[sig(jt, 4*q + r)];
            P1[jt][r] = 0.f;
        }

    __asm__ volatile("" ::: "memory");   // pin LDS-sourced state in VGPRs

    const int b = 16*w + l;
    const float* xin = xg + b * (T_ * S_);
    float* llout = out + (size_t)b * T_ * U_ + u;

    const floatx4 z = {0.f, 0.f, 0.f, 0.f};
    floatx4 ssvA = z, ssvB = z;          // prev step's ones-MFMA half-sums

    auto dot4 = [](const floatx4& cb, const floatx4& x4) {
        return fmaf(cb.x, x4.x, fmaf(cb.y, x4.y, fmaf(cb.z, x4.z, cb.w * x4.w)));
    };

    // E ping-pong buffers: EvA = even slots, EvB = odd slots (lag-2 fill)
    floatx4 EvA[4], EvB[4];

    // ---------------- pipeline fill: E_0 and E_1 (VALU) ----------------
    {
        floatx4 x0 = *(const floatx4*)xin;
        #pragma unroll
        for (int jt = 0; jt < 4; ++jt)
            #pragma unroll
            for (int r = 0; r < 4; ++r)
                EvA[jt][r] = dot4(cBem[jt][r], x0);
    }
    floatx4 xvA[4], xvB[4];
    #pragma unroll
    for (int i = 0; i < 4; ++i)
        xvA[i] = *(const floatx4*)(xin + (1 + i) * S_);   // x_1..x_4 raw
    {
        floatx4 x1 = xvA[0];
        #pragma unroll
        for (int jt = 0; jt < 4; ++jt)
            #pragma unroll
            for (int r = 0; r < 4; ++r)
                EvB[jt][r] = dot4(cBem[jt][r], x1);
    }

    float hist[8];
    float ssf = 1.0f;
    float fcur = 1.0f;
    float Cacc = 0.f;
    float offacc = 0.f, sumk = 0.f;

    // one HMM step. xr2 = raw x_{t+2}; Ein = E_t (read), Eout = E_{t+2}
    // (written; same buffer as Ein — read-before-write). slot is a literal
    // at every call site -> all slot branches constant-fold.
    auto step = [&](const floatx4& xr2, int slot, bool own, bool ownP,
                    const floatx4* Ein, floatx4* Eout) {
        // ---------- V phase (reads ordered oldest-first) ----------
        // 1) consume prev step's ss (ones-MFMAs, cover ~2 MFMA slots +)
        {
            float ssp = ssvA[0] + ssvB[0];
            if (slot == 0) {
                hist[7] = ownP ? ssp : hist[7];
            } else {
                hist[slot - 1] = own ? ssp : hist[slot - 1];
                if (slot == 6) ssf = ssp;   // slot-5 ss, 2 steps of slack
            }
        }

        // 2) Rv = P0+P1 (prev-M R-MFMAs, oldest), gv = Ev o Rv (Ev lag-2)
        floatx4 gv[4];
        #pragma unroll
        for (int jt = 0; jt < 4; ++jt) {
            floatx4 Rv = P0[jt] + P1[jt];
            gv[jt] = Ein[jt] * Rv;
        }
        if (slot == 0) {                 // octet pow2 rescale (folded only here)
            #pragma unroll
            for (int jt = 0; jt < 4; ++jt) gv[jt] *= fcur;
        }

        // 3) packs
        bf16x8 bf0, bf1;
        #pragma unroll
        for (int pp = 0; pp < 4; ++pp) {
            bf0[pp]     = (__bf16)gv[0][pp];
            bf0[4 + pp] = (__bf16)gv[1][pp];
            bf1[pp]     = (__bf16)gv[2][pp];
            bf1[4 + pp] = (__bf16)gv[3][pp];
        }

        // ---------- M phase: 10 mutually independent MFMAs ----------
        #pragma unroll
        for (int jt = 0; jt < 4; ++jt)
            P0[jt] = __builtin_amdgcn_mfma_f32_16x16x32_bf16(afrag[jt][0], bf0, z, 0, 0, 0);
        #pragma unroll
        for (int jt = 0; jt < 4; ++jt)
            P1[jt] = __builtin_amdgcn_mfma_f32_16x16x32_bf16(afrag[jt][1], bf1, z, 0, 0, 0);

        // E_{t+2} on the VALU (independent of everything in M(t);
        // schedulable into the MFMA issue shadow)
        #pragma unroll
        for (int jt = 0; jt < 4; ++jt)
            #pragma unroll
            for (int r = 0; r < 4; ++r)
                Eout[jt][r] = dot4(cBem[jt][r], xr2);

        ssvA = __builtin_amdgcn_mfma_f32_16x16x32_bf16(onesf, bf0, z, 0, 0, 0);
        ssvB = __builtin_amdgcn_mfma_f32_16x16x32_bf16(onesf, bf1, z, 0, 0, 0);
    };

    // ---------------- T-loop: one octet per iteration ----------------
    #pragma unroll 1
    for (int tb = 0; tb < T_; tb += 8) {
        const int oct = (tb >> 3) & 3;
        const bool own  = (q == oct);
        const bool ownP = (q == ((oct + 3) & 3));

        #pragma unroll
        for (int i = 0; i < 4; ++i) {
            int ti = tb + 5 + i; ti = (ti < T_) ? ti : T_ - 1;
            xvB[i] = *(const floatx4*)(xin + ti * S_);
        }

        // slot s consumes x_{tb+s+2} for its lag-2 E
        step(xvA[1], 0, own, ownP, EvA, EvA);
        step(xvA[2], 1, own, ownP, EvB, EvB);
        step(xvA[3], 2, own, ownP, EvA, EvA);
        step(xvB[0], 3, own, ownP, EvB, EvB);

        #pragma unroll
        for (int i = 0; i < 4; ++i) {
            int ti = tb + 9 + i; ti = (ti < T_) ? ti : T_ - 1;
            xvA[i] = *(const floatx4*)(xin + ti * S_);
        }

        step(xvB[1], 4, own, ownP, EvA, EvA);
        step(xvB[2], 5, own, ownP, EvB, EvB);
        step(xvB[3], 6, own, ownP, EvA, EvA);
        step(xvA[0], 7, own, ownP, EvB, EvB);

        if (oct == 3) {   // pre-flush tail capture of slot 7 (once per 32)
            float ssp = ssvA[0] + ssvB[0];
            hist[7] = own ? ssp : hist[7];
        }

        // octet boundary: derive next pow2 rescale from ssraw_{slot5};
        // applied at next octet's slot 0 via gv *= fcur.
        {
            unsigned eb = (__float_as_uint(ssf) >> 23) & 255u;
            fcur = __uint_as_float((254u - eb) << 23);
            float kf = (float)((int)eb - 127);
            offacc += (q > oct) ? kf : 0.f;   // octets before lane q's octet
            sumk   += kf;
        }

        // ---------------- flush: ll_t = log(ssraw_t) + correction -------
        if (oct == 3) {
            float base = Cacc + LN2F * offacc;
            float* fp = llout + (size_t)(tb - 24 + 8 * q) * U_;
            #pragma unroll
            for (int k = 0; k < 8; ++k)
                fp[(size_t)k * U_] = __logf(hist[k]) + base;
            Cacc += LN2F * sumk;
            offacc = 0.f; sumk = 0.f;
        }
    }
}

extern "C" void kernel_launch(void* const* d_in, const int* in_sizes, int n_in,
                              void* d_out, int out_size, void* d_ws, size_t ws_size,
                              hipStream_t stream) {
    const float* xg    = (const float*)d_in[0];
    const float* trans = (const float*)d_in[1];
    const float* emis  = (const float*)d_in[2];
    const float* initk = (const float*)d_in[3];
    float* out = (float*)d_out;
    hipLaunchKernelGGL(hmm_fwd_kernel, dim3(U_), dim3(256), 0, stream,
                       xg, trans, emis, initk, out);
}

// Round 11
// 369.948 us; speedup vs baseline: 1.0096x; 1.0096x over previous
//
#include <hip/hip_runtime.h>

// HMM forward scan, one workgroup per unit u. U=256, N=64, S=4, B=64, T=1024.
// Wave w owns batches [16w,16w+16); lane (q=lane>>4,l=lane&15) owns batch
// b=16w+l and the 16 states j = sig(jt, 4q+r).
//
// R19 = R17 chassis + ss-from-R (row-stochastic identity).
// A is row-stochastic => sum_j R_{t+1}[j] = sum_i g_t[i] = ss_t. So the 2
// ones-row ss-MFMAs are redundant: ss is the in-lane+cross-q sum of
// Rv = P0+P1, which V(t+1) computes anyway. 12 MFMAs/step (8 R unchained
// + 4 E lag-2), all reads with >=85cy slack:
//  - V(t): consume shfls issued at V(t-1) (DS, ~1 step old: no hazard)
//    -> ss_{t-2}; capture hist[slot-2] (slots 0,1 -> hist[6],[7] of the
//    PREVIOUS octet, ownP; stale cross-block writes are overwritten by
//    the oct-3 tail before any flush).
//  - V(t): Rv=P0+P1 (cover = 4 E-MFMA issues + consume ops), gv, packs,
//    then in-lane Rv-sum + 3 parallel shfl_xor(16/32/48) issued pre-M.
//  - oct==3 tail: consume slot-7 shfls -> hist[6]; recompute current
//    Rv-sum + shfls + immediate wait -> hist[7] (exposed once per 32).
//  - ssf (= hist[5] value) captured at slot 7; fcur derived at boundary,
//    applied at next slot 0 (R17).
// Numerics: ss now carries bf16(A)-row-sum error (~1 +- 2^-9) — bounded
// ll drift well inside the passing tolerance. E lag-2 + slot-0-only
// rescale unchanged from R17 (proven).

#define U_ 256
#define N_ 64
#define S_ 4
#define B_ 64
#define T_ 1024
#define ROWP 72
#define LN2F 0.69314718055994530942f

typedef __attribute__((ext_vector_type(8))) __bf16 bf16x8;
typedef __attribute__((ext_vector_type(4))) float floatx4;

__device__ __forceinline__ int sig(int jt, int m) {
    return 32 * (jt >> 1) + 4 * (jt & 1) + 8 * (m >> 2) + (m & 3);
}

__launch_bounds__(256, 1)
__global__ void hmm_fwd_kernel(const float* __restrict__ xg,     // [B][T][S]
                               const float* __restrict__ trans,  // [U][N][N]
                               const float* __restrict__ emis,   // [U][N][S]
                               const float* __restrict__ initk,  // [U][N]
                               float* __restrict__ out)          // [B][T][U]
{
    __shared__ __bf16 AT[N_ * ROWP];
    __shared__ float BemS[N_][S_];
    __shared__ float IS[N_];

    const int bid = blockIdx.x;
    const int u = ((bid & 7) << 5) | (bid >> 3);   // XCD-aware u swizzle
    const int tid = threadIdx.x;
    const int lane = tid & 63;
    const int w = tid >> 6;
    const int q = lane >> 4;
    const int l = lane & 15;

    // ---------------- prologue: softmaxes (one-time) ----------------
    if (tid < 64) {
        const float* rowp = trans + (u * N_ + tid) * N_;
        float v[N_];
        #pragma unroll
        for (int k = 0; k < 16; ++k) {
            floatx4 t4 = *(const floatx4*)(rowp + 4 * k);
            v[4*k] = t4.x; v[4*k+1] = t4.y; v[4*k+2] = t4.z; v[4*k+3] = t4.w;
        }
        float m = v[0];
        #pragma unroll
        for (int j = 1; j < N_; ++j) m = fmaxf(m, v[j]);
        float s = 0.f;
        #pragma unroll
        for (int j = 0; j < N_; ++j) { v[j] = __expf(v[j] - m); s += v[j]; }
        float inv = 1.0f / s;
        #pragma unroll
        for (int j = 0; j < N_; ++j) AT[j * ROWP + tid] = (__bf16)(v[j] * inv);
    } else if (tid < 128) {
        int n = tid - 64;
        floatx4 e4 = *(const floatx4*)(emis + (u * N_ + n) * S_);
        float m = fmaxf(fmaxf(e4.x, e4.y), fmaxf(e4.z, e4.w));
        float a = __expf(e4.x - m), b2 = __expf(e4.y - m);
        float c = __expf(e4.z - m), d = __expf(e4.w - m);
        float inv = 1.0f / (a + b2 + c + d);
        BemS[n][0] = a*inv; BemS[n][1] = b2*inv; BemS[n][2] = c*inv; BemS[n][3] = d*inv;
    } else if (tid < 192) {
        int j = tid - 128;
        float v = initk[u * N_ + j];
        float m = v;
        #pragma unroll
        for (int s = 1; s < 64; s <<= 1) m = fmaxf(m, __shfl_xor(m, s, 64));
        float e = __expf(v - m);
        float ssum = e;
        #pragma unroll
        for (int s = 1; s < 64; s <<= 1) ssum += __shfl_xor(ssum, s, 64);
        IS[j] = e / ssum;
    }
    __syncthreads();

    // ------------- persistent register state -------------
    bf16x8 afrag[4][2];
    #pragma unroll
    for (int jt = 0; jt < 4; ++jt)
        #pragma unroll
        for (int kt = 0; kt < 2; ++kt)
            afrag[jt][kt] = *(const bf16x8*)&AT[sig(jt, l) * ROWP + 32*kt + 8*q];

    bf16x8 afragE[4];
    #pragma unroll
    for (int jt = 0; jt < 4; ++jt) {
        #pragma unroll
        for (int pp = 0; pp < 8; ++pp) afragE[jt][pp] = (__bf16)0.f;
        if (q == 0) {
            #pragma unroll
            for (int c = 0; c < 4; ++c)
                afragE[jt][c] = (__bf16)BemS[sig(jt, l)][c];
        }
    }

    // Rv(t) = P0+P1 combined lag-1 on VALU (R13, unchained)
    floatx4 P0[4], P1[4];
    #pragma unroll
    for (int jt = 0; jt < 4; ++jt)
        #pragma unroll
        for (int r = 0; r < 4; ++r) {
            P0[jt][r] = IS[sig(jt, 4*q + r)];
            P1[jt][r] = 0.f;
        }

    __asm__ volatile("" ::: "memory");   // pin LDS-sourced state in VGPRs

    const int b = 16*w + l;
    const float* xin = xg + b * (T_ * S_);
    float* llout = out + (size_t)b * T_ * U_ + u;

    const floatx4 z = {0.f, 0.f, 0.f, 0.f};

    bf16x8 be;
    #pragma unroll
    for (int pp = 0; pp < 8; ++pp) be[pp] = (__bf16)0.f;   // hi half stays 0

    // E ping-pong buffers: EvA = even slots, EvB = odd slots (lag-2 fill)
    floatx4 EvA[4], EvB[4];

    // ---------------- pipeline fill: E_0 and E_1 ----------------
    {
        floatx4 x0 = *(const floatx4*)xin;
        be[0] = (__bf16)x0.x; be[1] = (__bf16)x0.y;
        be[2] = (__bf16)x0.z; be[3] = (__bf16)x0.w;
        #pragma unroll
        for (int jt = 0; jt < 4; ++jt)
            EvA[jt] = __builtin_amdgcn_mfma_f32_16x16x32_bf16(afragE[jt], be, z, 0, 0, 0);
    }
    floatx4 xvA[4], xvB[4];
    #pragma unroll
    for (int i = 0; i < 4; ++i)
        xvA[i] = *(const floatx4*)(xin + (1 + i) * S_);   // x_1..x_4 raw
    {
        floatx4 x1 = xvA[0];
        be[0] = (__bf16)x1.x; be[1] = (__bf16)x1.y;
        be[2] = (__bf16)x1.z; be[3] = (__bf16)x1.w;
        #pragma unroll
        for (int jt = 0; jt < 4; ++jt)
            EvB[jt] = __builtin_amdgcn_mfma_f32_16x16x32_bf16(afragE[jt], be, z, 0, 0, 0);
    }

    float hist[8];
    float ssf = 1.0f;
    float fcur = 1.0f;
    float pp0s = 0.f, pa16s = 0.f, pa32s = 0.f, pa48s = 0.f;
    float Cacc = 0.f;
    float offacc = 0.f, sumk = 0.f;

    // one HMM step. xr2 = raw x_{t+2}; Ein = E_t (read), Eout = E_{t+2}.
    // slot is a literal at every call site -> all branches constant-fold.
    auto step = [&](const floatx4& xr2, int slot, bool own, bool ownP,
                    const floatx4* Ein, floatx4* Eout) {
        // ---------- V phase ----------
        // 1) consume shfls issued at V(t-1): ss_{t-2} (DS results, 1 step
        //    old -> fully covered, no MFMA hazard)
        {
            float ss = (pp0s + pa16s) + (pa32s + pa48s);
            if (slot == 0) {
                hist[6] = ownP ? ss : hist[6];
            } else if (slot == 1) {
                hist[7] = ownP ? ss : hist[7];
            } else {
                hist[slot - 2] = own ? ss : hist[slot - 2];
            }
            if (slot == 7) ssf = ss;     // = hist[5] value; 2 slots of slack
        }

        // 2) Rv = P0+P1 (prev-M R-MFMAs; cover = 4 E issues + consume ops)
        floatx4 Rv[4];
        #pragma unroll
        for (int jt = 0; jt < 4; ++jt) Rv[jt] = P0[jt] + P1[jt];

        floatx4 gv[4];
        #pragma unroll
        for (int jt = 0; jt < 4; ++jt) gv[jt] = Ein[jt] * Rv[jt];
        if (slot == 0) {                 // octet pow2 rescale (folded only here)
            #pragma unroll
            for (int jt = 0; jt < 4; ++jt) gv[jt] *= fcur;
        }

        // 3) packs
        bf16x8 bf0, bf1;
        #pragma unroll
        for (int pp = 0; pp < 4; ++pp) {
            bf0[pp]     = (__bf16)gv[0][pp];
            bf0[4 + pp] = (__bf16)gv[1][pp];
            bf1[pp]     = (__bf16)gv[2][pp];
            bf1[4 + pp] = (__bf16)gv[3][pp];
        }
        be[0] = (__bf16)xr2.x; be[1] = (__bf16)xr2.y;
        be[2] = (__bf16)xr2.z; be[3] = (__bf16)xr2.w;

        // 4) issue ss_{t-1} reduce: sum_j R_t (row-stochastic identity);
        //    3 parallel shfls over q-groups, consumed at V(t+1)
        {
            floatx4 s4r = (Rv[0] + Rv[1]) + (Rv[2] + Rv[3]);
            pp0s  = (s4r.x + s4r.y) + (s4r.z + s4r.w);
            pa16s = __shfl_xor(pp0s, 16, 64);
            pa32s = __shfl_xor(pp0s, 32, 64);
            pa48s = __shfl_xor(pp0s, 48, 64);
        }

        // ---------- M phase: 12 mutually independent MFMAs ----------
        #pragma unroll
        for (int jt = 0; jt < 4; ++jt)
            P0[jt] = __builtin_amdgcn_mfma_f32_16x16x32_bf16(afrag[jt][0], bf0, z, 0, 0, 0);
        #pragma unroll
        for (int jt = 0; jt < 4; ++jt)
            P1[jt] = __builtin_amdgcn_mfma_f32_16x16x32_bf16(afrag[jt][1], bf1, z, 0, 0, 0);
        #pragma unroll
        for (int jt = 0; jt < 4; ++jt)
            Eout[jt] = __builtin_amdgcn_mfma_f32_16x16x32_bf16(afragE[jt], be, z, 0, 0, 0);
    };

    // ---------------- T-loop: one octet per iteration ----------------
    #pragma unroll 1
    for (int tb = 0; tb < T_; tb += 8) {
        const int oct = (tb >> 3) & 3;
        const bool own  = (q == oct);
        const bool ownP = (q == ((oct + 3) & 3));

        #pragma unroll
        for (int i = 0; i < 4; ++i) {
            int ti = tb + 5 + i; ti = (ti < T_) ? ti : T_ - 1;
            xvB[i] = *(const floatx4*)(xin + ti * S_);
        }

        // slot s consumes x_{tb+s+2} for its lag-2 E
        step(xvA[1], 0, own, ownP, EvA, EvA);
        step(xvA[2], 1, own, ownP, EvB, EvB);
        step(xvA[3], 2, own, ownP, EvA, EvA);
        step(xvB[0], 3, own, ownP, EvB, EvB);

        #pragma unroll
        for (int i = 0; i < 4; ++i) {
            int ti = tb + 9 + i; ti = (ti < T_) ? ti : T_ - 1;
            xvA[i] = *(const floatx4*)(xin + ti * S_);
        }

        step(xvB[1], 4, own, ownP, EvA, EvA);
        step(xvB[2], 5, own, ownP, EvB, EvB);
        step(xvB[3], 6, own, ownP, EvA, EvA);
        step(xvA[0], 7, own, ownP, EvB, EvB);

        if (oct == 3) {
            // tail 1: consume slot-7-issued shfls -> ss_{tb+6} -> hist[6]
            {
                float ss6 = (pp0s + pa16s) + (pa32s + pa48s);
                hist[6] = own ? ss6 : hist[6];
            }
            // tail 2: ss_{tb+7} = sum_j R_{tb+8} (current P0/P1); exposed
            // shfl wait once per 32 steps.
            {
                floatx4 Rt[4];
                #pragma unroll
                for (int jt = 0; jt < 4; ++jt) Rt[jt] = P0[jt] + P1[jt];
                floatx4 s4r = (Rt[0] + Rt[1]) + (Rt[2] + Rt[3]);
                pp0s  = (s4r.x + s4r.y) + (s4r.z + s4r.w);
                pa16s = __shfl_xor(pp0s, 16, 64);
                pa32s = __shfl_xor(pp0s, 32, 64);
                pa48s = __shfl_xor(pp0s, 48, 64);
                float ss7 = (pp0s + pa16s) + (pa32s + pa48s);
                hist[7] = own ? ss7 : hist[7];
            }
        }

        // octet boundary: derive next pow2 rescale from ssraw_{slot5};
        // applied at next octet's slot 0 via gv *= fcur.
        {
            unsigned eb = (__float_as_uint(ssf) >> 23) & 255u;
            fcur = __uint_as_float((254u - eb) << 23);
            float kf = (float)((int)eb - 127);
            offacc += (q > oct) ? kf : 0.f;   // octets before lane q's octet
            sumk   += kf;
        }

        // ---------------- flush: ll_t = log(ssraw_t) + correction -------
        if (oct == 3) {
            float base = Cacc + LN2F * offacc;
            float* fp = llout + (size_t)(tb - 24 + 8 * q) * U_;
            #pragma unroll
            for (int k = 0; k < 8; ++k)
                fp[(size_t)k * U_] = __logf(hist[k]) + base;
            Cacc += LN2F * sumk;
            offacc = 0.f; sumk = 0.f;
        }
    }
}

extern "C" void kernel_launch(void* const* d_in, const int* in_sizes, int n_in,
                              void* d_out, int out_size, void* d_ws, size_t ws_size,
                              hipStream_t stream) {
    const float* xg    = (const float*)d_in[0];
    const float* trans = (const float*)d_in[1];
    const float* emis  = (const float*)d_in[2];
    const float* initk = (const float*)d_in[3];
    float* out = (float*)d_out;
    hipLaunchKernelGGL(hmm_fwd_kernel, dim3(U_), dim3(256), 0, stream,
                       xg, trans, emis, initk, out);
}